// Round 9
// baseline (570.142 us; speedup 1.0000x reference)
//
#include <hip/hip_runtime.h>

#define NNODES 100000
#define F 256
#define NBKT ((NNODES + 127) / 128)    // 782 buckets of 128 src nodes
#define BKT_CAP 5000                   // mean 4092, +14 sigma; P(overflow) ~ 1e-40
#define CHUNK_A 8192                   // edges per binning block (391 blocks @ 3.2M)

typedef unsigned short u16;
typedef unsigned int   u32;
typedef __attribute__((ext_vector_type(8))) short short8v;          // 8 bf16
typedef __attribute__((ext_vector_type(8))) unsigned short ushort8; // 8 bf16 bits
typedef __attribute__((ext_vector_type(4))) float f32x4;
typedef __attribute__((ext_vector_type(2))) float f32x2;

__device__ __forceinline__ u16 f2bf(float f) {
    u32 u = __float_as_uint(f);
    u32 r = u + 0x7FFFu + ((u >> 16) & 1u);   // round-to-nearest-even
    return (u16)(r >> 16);
}

// ---------------- cast W -> bf16 ----------------
__global__ __launch_bounds__(256) void cast_w(const float* __restrict__ W,
                                              u16* __restrict__ Wb) {
    int i = blockIdx.x * 256 + threadIdx.x;
    if (i >= F * F / 4) return;
    float4 w = ((const float4*)W)[i];
    ushort4 o;
    o.x = f2bf(w.x); o.y = f2bf(w.y); o.z = f2bf(w.z); o.w = f2bf(w.w);
    ((ushort4*)Wb)[i] = o;
}

// ---------------- cast X -> bf16 (streaming) ----------------
__global__ __launch_bounds__(256) void cast_x(const float* __restrict__ X,
                                              u16* __restrict__ Xb, int total4) {
    int i = blockIdx.x * 256 + threadIdx.x;
    if (i >= total4) return;
    float4 x = ((const float4*)X)[i];
    ushort4 o;
    o.x = f2bf(x.x); o.y = f2bf(x.y); o.z = f2bf(x.z); o.w = f2bf(x.w);
    ((ushort4*)Xb)[i] = o;
}

// ---------------- GEMM: Yb = bf16( Xb @ Wb^T ) via MFMA, LDS-staged ----------
// 128x128 tile, K staged in two 128-wide K-tiles. A+B = 64 KB LDS -> 2 blk/CU.
// 16B-chunk XOR swizzle (chunk ^= row&7) keeps ds_read_b128 <=2-way (free).
__global__ __launch_bounds__(256) void gemm_mfma(const u16* __restrict__ Xb,
                                                 const u16* __restrict__ Wb,
                                                 u16* __restrict__ Yb) {
    __shared__ u16 As[128 * 128];   // 32 KB
    __shared__ u16 Bs[128 * 128];   // 32 KB
    const int wv   = threadIdx.x >> 6;
    const int lane = threadIdx.x & 63;
    const int lm   = lane & 15;
    const int kg   = lane >> 4;
    const int m0   = blockIdx.x * 128;
    const int n0   = blockIdx.y * 128;

    f32x4 acc[2][8];
#pragma unroll
    for (int t = 0; t < 2; ++t)
#pragma unroll
        for (int u = 0; u < 8; ++u) acc[t][u] = (f32x4){0.f, 0.f, 0.f, 0.f};

#pragma unroll
    for (int kt = 0; kt < 2; ++kt) {
        if (kt) __syncthreads();          // protect LDS before overwrite
#pragma unroll
        for (int i = 0; i < 8; ++i) {
            int q   = i * 256 + threadIdx.x;
            int row = q >> 4;
            int cs  = (q & 15) ^ (row & 7);
            size_t goff = (size_t)row * 512 + kt * 256 + cs * 16;   // bytes
            *(ushort8*)&As[q * 8] = *(const ushort8*)((const char*)Xb + (size_t)m0 * 512 + goff);
            *(ushort8*)&Bs[q * 8] = *(const ushort8*)((const char*)Wb + (size_t)n0 * 512 + goff);
        }
        __syncthreads();
#pragma unroll
        for (int s = 0; s < 4; ++s) {     // 4 k-steps of 32 per K-tile
            short8v aF[2];
#pragma unroll
            for (int t = 0; t < 2; ++t) {
                int r = wv * 32 + t * 16 + lm;
                int c = (s * 4 + kg) ^ (r & 7);
                aF[t] = *(const short8v*)&As[r * 128 + c * 8];
            }
            short8v bF[8];
#pragma unroll
            for (int u = 0; u < 8; ++u) {
                int r = u * 16 + lm;
                int c = (s * 4 + kg) ^ (r & 7);
                bF[u] = *(const short8v*)&Bs[r * 128 + c * 8];
            }
#pragma unroll
            for (int t = 0; t < 2; ++t)
#pragma unroll
                for (int u = 0; u < 8; ++u)
                    acc[t][u] = __builtin_amdgcn_mfma_f32_16x16x32_bf16(aF[t], bF[u], acc[t][u], 0, 0, 0);
        }
    }

    // D layout (16x16x32): col = lane&15, row = (lane>>4)*4 + i
#pragma unroll
    for (int t = 0; t < 2; ++t) {
        int rbase = m0 + wv * 32 + t * 16 + kg * 4;
#pragma unroll
        for (int i = 0; i < 4; ++i) {
            int row = rbase + i;
            if (row < NNODES) {
#pragma unroll
                for (int u = 0; u < 8; ++u)
                    Yb[(size_t)row * F + n0 + u * 16 + lm] = f2bf(acc[t][u][i]);
            }
        }
    }
}

// ========== Deterministic binning: NO global atomics (count/scan/write) ======

// ---- step 1: per-block bucket histogram -> counts[blk][NBKT] ----
__global__ __launch_bounds__(256) void bin_count(const int* __restrict__ src,
                                                 int* __restrict__ counts,
                                                 int n_edges) {
    __shared__ int hist[NBKT];
    const int e0 = blockIdx.x * CHUNK_A;
    for (int i = threadIdx.x; i < NBKT; i += 256) hist[i] = 0;
    __syncthreads();
#pragma unroll
    for (int k = 0; k < 32; ++k) {
        int e = e0 + k * 256 + threadIdx.x;
        if (e < n_edges) atomicAdd(&hist[src[e] >> 7], 1);
    }
    __syncthreads();
    for (int i = threadIdx.x; i < NBKT; i += 256)
        counts[(size_t)blockIdx.x * NBKT + i] = hist[i];
}

// ---- step 2: per-bucket exclusive scan over blocks (one block per bucket) ----
// counts[blk][b] <- b*BKT_CAP + prefix; bktcnt[b] = total. nblk <= 512.
__global__ __launch_bounds__(256) void bin_scan(int* __restrict__ counts,
                                                int* __restrict__ bktcnt, int nblk) {
    __shared__ int s[512];
    const int b = blockIdx.x;
    const int t = threadIdx.x;
    int v0 = (t < nblk)       ? counts[(size_t)t * NBKT + b]         : 0;
    int v1 = (t + 256 < nblk) ? counts[(size_t)(t + 256) * NBKT + b] : 0;
    s[t] = v0; s[t + 256] = v1;
    __syncthreads();
    for (int off = 1; off < 512; off <<= 1) {
        int a0 = (t >= off) ? s[t - off] : 0;
        int a1 = (t + 256 >= off) ? s[t + 256 - off] : 0;
        __syncthreads();
        s[t] += a0; s[t + 256] += a1;
        __syncthreads();
    }
    const int base = b * BKT_CAP;
    if (t < nblk)       counts[(size_t)t * NBKT + b]         = base + s[t] - v0;
    if (t + 256 < nblk) counts[(size_t)(t + 256) * NBKT + b] = base + s[t + 256] - v1;
    if (t == 255) bktcnt[b] = s[511];
}

// ---- step 3: re-histogram for local slots, write temp deterministically ----
// temp[pos] = ( (src&127)<<20 | dst , val_bits )
__global__ __launch_bounds__(256) void bin_write(const int* __restrict__ src,
                                                 const int* __restrict__ dst,
                                                 const float* __restrict__ val,
                                                 const int* __restrict__ counts,
                                                 int2* __restrict__ temp, int n_edges) {
    __shared__ int hist[NBKT];
    const int e0 = blockIdx.x * CHUNK_A;
    for (int i = threadIdx.x; i < NBKT; i += 256) hist[i] = 0;
    __syncthreads();
    u32 lpk[32];
#pragma unroll
    for (int k = 0; k < 32; ++k) {
        int e = e0 + k * 256 + threadIdx.x;
        if (e < n_edges) {
            int s = src[e];
            int bkt = s >> 7;
            int l = atomicAdd(&hist[bkt], 1);          // < 8192, fits 13 bits
            lpk[k] = (u32)l | ((u32)(s & 127) << 13) | ((u32)bkt << 20);
        }
    }
    // no sync needed: each thread consumes only its own lpk; counts is read-only
#pragma unroll
    for (int k = 0; k < 32; ++k) {
        int e = e0 + k * 256 + threadIdx.x;
        if (e < n_edges) {
            u32 p   = lpk[k];
            int bkt = (int)(p >> 20);
            int pos = counts[(size_t)blockIdx.x * NBKT + bkt] + (int)(p & 0x1FFFu);
            int sl  = (int)((p >> 13) & 127u);
            if (pos < (bkt + 1) * BKT_CAP)             // overflow guard
                temp[pos] = make_int2((sl << 20) | dst[e], __float_as_int(val[e]));
        }
    }
}

// ---------------- per-bucket node sort + nodeseg emit ----------------
// Bucket staged in LDS; pack.x holds PRE-SCALED byte offset dst*512.
__global__ __launch_bounds__(256) void sort_bucket(const int* __restrict__ bktcnt,
                                                   const int2* __restrict__ temp,
                                                   int2* __restrict__ pack,
                                                   int2* __restrict__ nodeseg) {
    __shared__ int2 tl[BKT_CAP];     // 39 KB
    __shared__ int h[128];
    __shared__ int curl[128];
    const int b = blockIdx.x;
    const int base = b * BKT_CAP;
    int cnt = bktcnt[b];
    if (cnt > BKT_CAP) cnt = BKT_CAP;   // overflow guard
    const int tid = threadIdx.x;

    if (tid < 128) h[tid] = 0;
    __syncthreads();
    for (int j = tid; j < cnt; j += 256) {     // stage + histogram in one pass
        int2 t = temp[base + j];
        tl[j] = t;
        atomicAdd(&h[t.x >> 20], 1);
    }
    __syncthreads();
    // inclusive scan over 128 entries
    for (int off = 1; off < 128; off <<= 1) {
        int x = 0;
        if (tid < 128 && tid >= off) x = h[tid - off];
        __syncthreads();
        if (tid < 128) h[tid] += x;
        __syncthreads();
    }
    if (tid < 128) {
        int incl = h[tid];
        int prev = tid ? h[tid - 1] : 0;
        curl[tid] = base + prev;
        int node = b * 128 + tid;
        if (node < NNODES) nodeseg[node] = make_int2(base + prev, base + incl);
    }
    __syncthreads();
    for (int j = tid; j < cnt; j += 256) {
        int2 p = tl[j];
        int loc = p.x >> 20;
        int pos = atomicAdd(&curl[loc], 1);
        pack[pos] = make_int2((p.x & 0xFFFFF) << 9, p.y);   // dst*512 byte offset
    }
}

// ---------------- Gather: out[node] = b + sum val * Y[dst]  (bf16 Y) --------
// Measured floor ~223 us across 3 schedules / 2 occupancies (fabric-bound).
__global__ __launch_bounds__(256) void gather_nodes(const int2* __restrict__ nodeseg,
                                                    const int2* __restrict__ pack,
                                                    const u16* __restrict__ Yb,
                                                    const float* __restrict__ bias,
                                                    float* __restrict__ out) {
    int node = blockIdx.x * 4 + (threadIdx.x >> 6);
    if (node >= NNODES) return;
    const int lane = threadIdx.x & 63;
    const int half = lane >> 5;
    const int l5   = lane & 31;
    const u32 loff = (u32)l5 * 16u;          // lane's byte offset within a row
    const char* Ybc = (const char*)Yb;

    int2 seg = nodeseg[node];
    const int beg = seg.x, end = seg.y;

    f32x2 acc2[4];
#pragma unroll
    for (int i = 0; i < 4; ++i) acc2[i] = (f32x2){0.f, 0.f};

    for (int j = beg; j < end; j += 16) {     // 8 pairs = 16 edges per iter
        u32 off[8];
        float v[8];
        ushort8 y[8];
#pragma unroll
        for (int q = 0; q < 8; ++q) {
            int idx = j + 2 * q + half;
            int safe = idx < end ? idx : end - 1;
            long long raw = __builtin_nontemporal_load((const long long*)&pack[safe]);
            off[q] = (u32)((unsigned long long)raw & 0xFFFFFFFFull);
            v[q] = (idx < end) ? __int_as_float((int)(raw >> 32)) : 0.f;
        }
#pragma unroll
        for (int q = 0; q < 8; ++q)
            y[q] = *(const ushort8*)(Ybc + (off[q] + loff));
#pragma unroll
        for (int q = 0; q < 8; ++q) {
            f32x2 vv; vv[0] = v[q]; vv[1] = v[q];
            const u32* yp = (const u32*)&y[q];
#pragma unroll
            for (int i = 0; i < 4; ++i) {
                u32 pb = yp[i];
                f32x2 yy;
                yy[0] = __uint_as_float(pb << 16);
                yy[1] = __uint_as_float(pb & 0xFFFF0000u);
                acc2[i] = __builtin_elementwise_fma(yy, vv, acc2[i]);
            }
        }
    }

    float acc[8];
#pragma unroll
    for (int i = 0; i < 4; ++i) { acc[2 * i] = acc2[i][0]; acc[2 * i + 1] = acc2[i][1]; }
    // combine halves
#pragma unroll
    for (int i = 0; i < 8; ++i) acc[i] += __shfl_xor(acc[i], 32);

    // bias + store: lane writes feats [l5*8 + half*4 .. +3]
    const int col = l5 * 8 + half * 4;
    float4 bv = *(const float4*)&bias[col];
    f32x4 o;
    o[0] = acc[half * 4 + 0] + bv.x;
    o[1] = acc[half * 4 + 1] + bv.y;
    o[2] = acc[half * 4 + 2] + bv.z;
    o[3] = acc[half * 4 + 3] + bv.w;
    __builtin_nontemporal_store(o, (f32x4*)&out[(size_t)node * F + col]);
}

extern "C" void kernel_launch(void* const* d_in, const int* in_sizes, int n_in,
                              void* d_out, int out_size, void* d_ws, size_t ws_size,
                              hipStream_t stream) {
    const float* X        = (const float*)d_in[0];
    const int*   edge_src = (const int*)d_in[1];
    const int*   edge_dst = (const int*)d_in[2];
    const float* edge_val = (const float*)d_in[3];
    const float* W        = (const float*)d_in[4];
    const float* b        = (const float*)d_in[5];
    float*       out      = (float*)d_out;
    const int n_edges     = in_sizes[1];
    const int nblk        = (n_edges + CHUNK_A - 1) / CHUNK_A;   // <= 512

    // Workspace (~116 MB): Yb | pack | temp | Wb | nodeseg | counts | bktcnt
    // Xb (51.25 MB) overlays pack+temp (62.6 MB): Xb dead after gemm.
    char* base = (char*)d_ws;
    const size_t ybBytes   = (size_t)NNODES * F * sizeof(u16);        // 51.2 MB
    const size_t packBytes = (size_t)NBKT * BKT_CAP * sizeof(int2);   // 31.3 MB
    u16*  Yb      = (u16*)base;
    int2* pack    = (int2*)(base + ybBytes);
    int2* temp    = (int2*)(base + ybBytes + packBytes);
    u16*  Xb      = (u16*)pack;                                       // overlay
    u16*  Wb      = (u16*)(base + ybBytes + 2 * packBytes);
    int2* nodeseg = (int2*)((char*)Wb + (size_t)F * F * sizeof(u16));
    int*  counts  = (int*)(nodeseg + NNODES);                         // nblk*NBKT
    int*  bktcnt  = counts + (size_t)nblk * NBKT;

    // 1) casts
    cast_w<<<(F * F / 4 + 255) / 256, 256, 0, stream>>>(W, Wb);
    int xt4 = NNODES * F / 4;
    cast_x<<<(xt4 + 255) / 256, 256, 0, stream>>>(X, Xb, xt4);

    // 2) Yb = bf16(Xb @ Wb^T) via LDS-staged MFMA
    dim3 ggrid((NNODES + 127) / 128, F / 128);
    gemm_mfma<<<ggrid, 256, 0, stream>>>(Xb, Wb, Yb);

    // 3) deterministic binning (no global atomics) + per-bucket sort
    bin_count<<<nblk, 256, 0, stream>>>(edge_src, counts, n_edges);
    bin_scan<<<NBKT, 256, 0, stream>>>(counts, bktcnt, nblk);
    bin_write<<<nblk, 256, 0, stream>>>(edge_src, edge_dst, edge_val, counts, temp, n_edges);
    sort_bucket<<<NBKT, 256, 0, stream>>>(bktcnt, temp, pack, nodeseg);

    // 4) Gather + bias
    gather_nodes<<<(NNODES + 3) / 4, 256, 0, stream>>>(nodeseg, pack, Yb, b, out);
}

// Round 10
// 555.896 us; speedup vs baseline: 1.0256x; 1.0256x over previous
//
#include <hip/hip_runtime.h>

#define NNODES 100000
#define F 256
#define NBKT ((NNODES + 127) / 128)    // 782 buckets of 128 src nodes
#define BKT_CAP 5120                   // mean 4092, +16 sigma
#define CHUNK_A 8192                   // edges per bin_edges block

typedef unsigned short u16;
typedef unsigned int   u32;
typedef __attribute__((ext_vector_type(8))) short short8v;          // 8 bf16
typedef __attribute__((ext_vector_type(8))) unsigned short ushort8; // 8 bf16 bits
typedef __attribute__((ext_vector_type(4))) float f32x4;
typedef __attribute__((ext_vector_type(2))) float f32x2;

// async global->LDS, 16B per lane; dst must be wave-uniform base (+lane*16 by HW)
#define GLDS(g, l) __builtin_amdgcn_global_load_lds(                                \
    (const __attribute__((address_space(1))) void*)(g),                             \
    (__attribute__((address_space(3))) void*)(l), 16, 0, 0)

__device__ __forceinline__ u16 f2bf(float f) {
    u32 u = __float_as_uint(f);
    u32 r = u + 0x7FFFu + ((u >> 16) & 1u);   // round-to-nearest-even
    return (u16)(r >> 16);
}

// ---------------- cast W -> bf16 + init bucket cursors (fused) ----------------
__global__ __launch_bounds__(256) void cast_w_init(const float* __restrict__ W,
                                                   u16* __restrict__ Wb,
                                                   int* __restrict__ cur) {
    int i = blockIdx.x * 256 + threadIdx.x;
    if (i < F * F / 4) {
        float4 w = ((const float4*)W)[i];
        ushort4 o;
        o.x = f2bf(w.x); o.y = f2bf(w.y); o.z = f2bf(w.z); o.w = f2bf(w.w);
        ((ushort4*)Wb)[i] = o;
    }
    if (i < NBKT) cur[i] = i * BKT_CAP;
}

// ---------------- cast X -> bf16 (streaming) ----------------
__global__ __launch_bounds__(256) void cast_x(const float* __restrict__ X,
                                              u16* __restrict__ Xb, int total4) {
    int i = blockIdx.x * 256 + threadIdx.x;
    if (i >= total4) return;
    float4 x = ((const float4*)X)[i];
    ushort4 o;
    o.x = f2bf(x.x); o.y = f2bf(x.y); o.z = f2bf(x.z); o.w = f2bf(x.w);
    ((ushort4*)Xb)[i] = o;
}

// ---------------- GEMM: Yb = bf16( Xb @ Wb^T ) via MFMA, LDS-staged ----------
// Staging now uses global_load_lds width=16 (no register round-trip, no per-pair
// waitcnt): LDS dest linear (wave-uniform base + lane*16), swizzle applied on
// the per-lane GLOBAL source address (cs invariant across the 8 steps).
// Compute phase identical to the verified round-7 kernel.
__global__ __launch_bounds__(256) void gemm_mfma(const u16* __restrict__ Xb,
                                                 const u16* __restrict__ Wb,
                                                 u16* __restrict__ Yb) {
    __shared__ u16 As[128 * 128];   // 32 KB
    __shared__ u16 Bs[128 * 128];   // 32 KB
    const int tid  = threadIdx.x;
    const int wv   = tid >> 6;
    const int lane = tid & 63;
    const int lm   = lane & 15;
    const int kg   = lane >> 4;
    const int m0   = blockIdx.x * 128;
    const int n0   = blockIdx.y * 128;

    // per-lane pre-swizzled global source: row = i*16 + (tid>>4), chunk cs
    const u32 csb = (u32)(((tid & 15) ^ ((tid >> 4) & 7)) * 16);
    const u32 rbb = (u32)((tid >> 4) * 512);
    const char* gA0 = (const char*)Xb + (size_t)m0 * 512 + rbb + csb;
    const char* gB0 = (const char*)Wb + (size_t)n0 * 512 + rbb + csb;
    const u32 wbase = (u32)(wv * 1024);      // wave-uniform LDS byte base

    f32x4 acc[2][8];
#pragma unroll
    for (int t = 0; t < 2; ++t)
#pragma unroll
        for (int u = 0; u < 8; ++u) acc[t][u] = (f32x4){0.f, 0.f, 0.f, 0.f};

#pragma unroll
    for (int kt = 0; kt < 2; ++kt) {
        if (kt) __syncthreads();          // protect LDS before overwrite
#pragma unroll
        for (int i = 0; i < 8; ++i) {     // 16 async 16B/lane issues, one drain
            GLDS(gA0 + kt * 256 + i * 8192, (char*)As + i * 4096 + wbase);
            GLDS(gB0 + kt * 256 + i * 8192, (char*)Bs + i * 4096 + wbase);
        }
        __syncthreads();                  // drains vmcnt + barrier
#pragma unroll
        for (int s = 0; s < 4; ++s) {     // 4 k-steps of 32 per K-tile
            short8v aF[2];
#pragma unroll
            for (int t = 0; t < 2; ++t) {
                int r = wv * 32 + t * 16 + lm;
                int c = (s * 4 + kg) ^ (r & 7);
                aF[t] = *(const short8v*)&As[r * 128 + c * 8];
            }
            short8v bF[8];
#pragma unroll
            for (int u = 0; u < 8; ++u) {
                int r = u * 16 + lm;
                int c = (s * 4 + kg) ^ (r & 7);
                bF[u] = *(const short8v*)&Bs[r * 128 + c * 8];
            }
#pragma unroll
            for (int t = 0; t < 2; ++t)
#pragma unroll
                for (int u = 0; u < 8; ++u)
                    acc[t][u] = __builtin_amdgcn_mfma_f32_16x16x32_bf16(aF[t], bF[u], acc[t][u], 0, 0, 0);
        }
    }

    // D layout (16x16x32): col = lane&15, row = (lane>>4)*4 + i
#pragma unroll
    for (int t = 0; t < 2; ++t) {
        int rbase = m0 + wv * 32 + t * 16 + kg * 4;
#pragma unroll
        for (int i = 0; i < 4; ++i) {
            int row = rbase + i;
            if (row < NNODES) {
#pragma unroll
                for (int u = 0; u < 8; ++u)
                    Yb[(size_t)row * F + n0 + u * 16 + lm] = f2bf(acc[t][u][i]);
            }
        }
    }
}

// ---------------- Phase A: bin edges into 128-node buckets ----------------
// temp[pos] = ( (src&127)<<20 | dst , val_bits ), bucket-strided regions.
// src read once: (l:13 | (src&127):7 | bkt:12) packed in registers.
__global__ __launch_bounds__(256) void bin_edges(const int* __restrict__ src,
                                                 const int* __restrict__ dst,
                                                 const float* __restrict__ val,
                                                 int* __restrict__ cur,
                                                 int2* __restrict__ temp,
                                                 int n_edges) {
    __shared__ int hist[NBKT];
    __shared__ int bas[NBKT];
    const int e0 = blockIdx.x * CHUNK_A;
    for (int i = threadIdx.x; i < NBKT; i += 256) hist[i] = 0;
    __syncthreads();

    u32 lpk[32];
#pragma unroll
    for (int k = 0; k < 32; ++k) {
        int e = e0 + k * 256 + threadIdx.x;
        if (e < n_edges) {
            int s = src[e];
            int bkt = s >> 7;
            int l = atomicAdd(&hist[bkt], 1);          // < 8192, fits 13 bits
            lpk[k] = (u32)l | ((u32)(s & 127) << 13) | ((u32)bkt << 20);
        }
    }
    __syncthreads();
    for (int i = threadIdx.x; i < NBKT; i += 256) {
        int c = hist[i];
        bas[i] = c ? atomicAdd(&cur[i], c) : 0;
    }
    __syncthreads();
#pragma unroll
    for (int k = 0; k < 32; ++k) {
        int e = e0 + k * 256 + threadIdx.x;
        if (e < n_edges) {
            u32 p   = lpk[k];
            int bkt = (int)(p >> 20);
            int pos = bas[bkt] + (int)(p & 0x1FFFu);
            int sl  = (int)((p >> 13) & 127u);
            temp[pos] = make_int2((sl << 20) | dst[e], __float_as_int(val[e]));
        }
    }
}

// ---------------- Phase B: per-bucket node sort + nodeseg emit ----------------
// Bucket staged in LDS; pack.x holds the PRE-SCALED byte offset dst*512.
__global__ __launch_bounds__(256) void sort_bucket(const int* __restrict__ cur,
                                                   const int2* __restrict__ temp,
                                                   int2* __restrict__ pack,
                                                   int2* __restrict__ nodeseg) {
    __shared__ int2 tl[BKT_CAP];     // 40 KB
    __shared__ int h[128];
    __shared__ int curl[128];
    const int b = blockIdx.x;
    const int base = b * BKT_CAP;
    int cnt = cur[b] - base;
    if (cnt > BKT_CAP) cnt = BKT_CAP;   // overflow guard
    const int tid = threadIdx.x;

    if (tid < 128) h[tid] = 0;
    __syncthreads();
    for (int j = tid; j < cnt; j += 256) {     // stage + histogram in one pass
        int2 t = temp[base + j];
        tl[j] = t;
        atomicAdd(&h[t.x >> 20], 1);
    }
    __syncthreads();
    // inclusive scan over 128 entries
    for (int off = 1; off < 128; off <<= 1) {
        int x = 0;
        if (tid < 128 && tid >= off) x = h[tid - off];
        __syncthreads();
        if (tid < 128) h[tid] += x;
        __syncthreads();
    }
    if (tid < 128) {
        int incl = h[tid];
        int prev = tid ? h[tid - 1] : 0;
        curl[tid] = base + prev;
        int node = b * 128 + tid;
        if (node < NNODES) nodeseg[node] = make_int2(base + prev, base + incl);
    }
    __syncthreads();
    for (int j = tid; j < cnt; j += 256) {
        int2 p = tl[j];
        int loc = p.x >> 20;
        int pos = atomicAdd(&curl[loc], 1);
        pack[pos] = make_int2((p.x & 0xFFFFF) << 9, p.y);   // dst*512 byte offset
    }
}

// ---------------- Gather: out[node] = b + sum val * Y[dst]  (bf16 Y) --------
// Measured floor ~223 us across 3 schedules / 2 occupancies (fabric-bound).
__global__ __launch_bounds__(256) void gather_nodes(const int2* __restrict__ nodeseg,
                                                    const int2* __restrict__ pack,
                                                    const u16* __restrict__ Yb,
                                                    const float* __restrict__ bias,
                                                    float* __restrict__ out) {
    int node = blockIdx.x * 4 + (threadIdx.x >> 6);
    if (node >= NNODES) return;
    const int lane = threadIdx.x & 63;
    const int half = lane >> 5;
    const int l5   = lane & 31;
    const u32 loff = (u32)l5 * 16u;          // lane's byte offset within a row
    const char* Ybc = (const char*)Yb;

    int2 seg = nodeseg[node];
    const int beg = seg.x, end = seg.y;

    f32x2 acc2[4];
#pragma unroll
    for (int i = 0; i < 4; ++i) acc2[i] = (f32x2){0.f, 0.f};

    for (int j = beg; j < end; j += 16) {     // 8 pairs = 16 edges per iter
        u32 off[8];
        float v[8];
        ushort8 y[8];
#pragma unroll
        for (int q = 0; q < 8; ++q) {
            int idx = j + 2 * q + half;
            int safe = idx < end ? idx : end - 1;
            long long raw = __builtin_nontemporal_load((const long long*)&pack[safe]);
            off[q] = (u32)((unsigned long long)raw & 0xFFFFFFFFull);
            v[q] = (idx < end) ? __int_as_float((int)(raw >> 32)) : 0.f;
        }
#pragma unroll
        for (int q = 0; q < 8; ++q)
            y[q] = *(const ushort8*)(Ybc + (off[q] + loff));
#pragma unroll
        for (int q = 0; q < 8; ++q) {
            f32x2 vv; vv[0] = v[q]; vv[1] = v[q];
            const u32* yp = (const u32*)&y[q];
#pragma unroll
            for (int i = 0; i < 4; ++i) {
                u32 pb = yp[i];
                f32x2 yy;
                yy[0] = __uint_as_float(pb << 16);
                yy[1] = __uint_as_float(pb & 0xFFFF0000u);
                acc2[i] = __builtin_elementwise_fma(yy, vv, acc2[i]);
            }
        }
    }

    float acc[8];
#pragma unroll
    for (int i = 0; i < 4; ++i) { acc[2 * i] = acc2[i][0]; acc[2 * i + 1] = acc2[i][1]; }
    // combine halves
#pragma unroll
    for (int i = 0; i < 8; ++i) acc[i] += __shfl_xor(acc[i], 32);

    // bias + store: lane writes feats [l5*8 + half*4 .. +3]
    const int col = l5 * 8 + half * 4;
    float4 bv = *(const float4*)&bias[col];
    f32x4 o;
    o[0] = acc[half * 4 + 0] + bv.x;
    o[1] = acc[half * 4 + 1] + bv.y;
    o[2] = acc[half * 4 + 2] + bv.z;
    o[3] = acc[half * 4 + 3] + bv.w;
    __builtin_nontemporal_store(o, (f32x4*)&out[(size_t)node * F + col]);
}

extern "C" void kernel_launch(void* const* d_in, const int* in_sizes, int n_in,
                              void* d_out, int out_size, void* d_ws, size_t ws_size,
                              hipStream_t stream) {
    const float* X        = (const float*)d_in[0];
    const int*   edge_src = (const int*)d_in[1];
    const int*   edge_dst = (const int*)d_in[2];
    const float* edge_val = (const float*)d_in[3];
    const float* W        = (const float*)d_in[4];
    const float* b        = (const float*)d_in[5];
    float*       out      = (float*)d_out;
    const int n_edges     = in_sizes[1];

    // Workspace (~116.2 MB). Xb (51.25 MB incl. OOB pad) overlays pack+temp:
    // Xb dead after gemm; temp/pack written only after gemm.
    char* base = (char*)d_ws;
    const size_t ybBytes   = (size_t)NNODES * F * sizeof(u16);        // 51.2 MB
    const size_t packBytes = (size_t)NBKT * BKT_CAP * sizeof(int2);   // 32.03 MB
    u16*  Yb      = (u16*)base;
    int2* pack    = (int2*)(base + ybBytes);
    int2* temp    = (int2*)(base + ybBytes + packBytes);
    u16*  Xb      = (u16*)pack;                                       // overlay
    u16*  Wb      = (u16*)(base + ybBytes + 2 * packBytes);
    int2* nodeseg = (int2*)((char*)Wb + (size_t)F * F * sizeof(u16));
    int*  cur     = (int*)(nodeseg + NNODES);

    // 1) W cast + cursor init (fused); X cast
    cast_w_init<<<(F * F / 4 + 255) / 256, 256, 0, stream>>>(W, Wb, cur);
    int xt4 = NNODES * F / 4;
    cast_x<<<(xt4 + 255) / 256, 256, 0, stream>>>(X, Xb, xt4);

    // 2) Yb = bf16(Xb @ Wb^T) via LDS-staged MFMA (async global_load_lds)
    dim3 ggrid((NNODES + 127) / 128, F / 128);
    gemm_mfma<<<ggrid, 256, 0, stream>>>(Xb, Wb, Yb);

    // 3) two-phase binned counting sort (no global scan)
    bin_edges<<<(n_edges + CHUNK_A - 1) / CHUNK_A, 256, 0, stream>>>(edge_src, edge_dst, edge_val,
                                                                     cur, temp, n_edges);
    sort_bucket<<<NBKT, 256, 0, stream>>>(cur, temp, pack, nodeseg);

    // 4) Gather + bias
    gather_nodes<<<(NNODES + 3) / 4, 256, 0, stream>>>(nodeseg, pack, Yb, b, out);
}